// Round 5
// baseline (120.607 us; speedup 1.0000x reference)
//
#include <hip/hip_runtime.h>
#include <math.h>

typedef __attribute__((ext_vector_type(2))) _Float16 half2v;

#define BB 4
#define HH 2048
#define WW 128
#define HP (HH + 2)   // 2050
#define WP (WW + 2)   // 130
#define PP 128        // pooled size
#define ROWS 4

#define BORDER_PER_B (2 * WP + 2 * (HP - 2))   // 4356

__device__ __forceinline__ half2v b2h(unsigned u) {
    return __builtin_bit_cast(half2v, u);
}
__device__ __forceinline__ unsigned pku(float a, float b) {
    return __builtin_bit_cast(unsigned, __builtin_amdgcn_cvt_pkrtz(a, b));
}
__device__ __forceinline__ float dot2(half2v a, unsigned wb, float c) {
    return __builtin_amdgcn_fdot2(a, b2h(wb), c, false);
}

// ---------------------------------------------------------------------------
// Kernel 0: zero the pad border of xph ([B][HP][WP] uint2 cells).
// Interior is fully overwritten by k_mat each call.
// ---------------------------------------------------------------------------
__global__ void k_pad(uint2* __restrict__ xph) {
    int i = blockIdx.x * 256 + threadIdx.x;
    if (i >= BB * BORDER_PER_B) return;
    int b = i / BORDER_PER_B;
    int r = i - b * BORDER_PER_B;
    int row, col;
    if (r < WP)          { row = 0;      col = r; }
    else if (r < 2 * WP) { row = HP - 1; col = r - WP; }
    else {
        int j = r - 2 * WP;
        row = 1 + (j >> 1);
        col = (j & 1) ? (WP - 1) : 0;
    }
    xph[((size_t)b * HP + row) * WP + col] = make_uint2(0u, 0u);
}

// ---------------------------------------------------------------------------
// Kernel 1: adaptive avg pool (exact 16x1 block mean) + 1x1 conv + sigmoid
// ---------------------------------------------------------------------------
__global__ void k_fm(const float* __restrict__ rgb, const float* __restrict__ w_fm,
                     float* __restrict__ fm) {
    int j = threadIdx.x;              // 0..127
    int bi = blockIdx.x;              // b*128 + i
    int b = bi >> 7, i = bi & 127;
    const float* r0 = rgb + ((size_t)(b * 2 + 0) * HH + (size_t)i * 16) * WW + j;
    const float* r1 = rgb + ((size_t)(b * 2 + 1) * HH + (size_t)i * 16) * WW + j;
    float s0 = 0.f, s1 = 0.f;
#pragma unroll
    for (int a = 0; a < 16; ++a) { s0 += r0[a * WW]; s1 += r1[a * WW]; }
    s0 *= (1.f / 16.f); s1 *= (1.f / 16.f);
    float f0 = w_fm[0] * s0 + w_fm[1] * s1;
    float f1 = w_fm[2] * s0 + w_fm[3] * s1;
    fm[((size_t)(b * 2 + 0) * PP + i) * PP + j] = 1.f / (1.f + expf(-f0));
    fm[((size_t)(b * 2 + 1) * PP + i) * PP + j] = 1.f / (1.f + expf(-f1));
}

// ---------------------------------------------------------------------------
// Kernel 2: mat = rgb @ fm + rgb (per b,c), fs = w_fs @ mat,
//           pack xph cell = half4 (sar0,sar1,fs0,fs1) as uint2.
// ---------------------------------------------------------------------------
__global__ __launch_bounds__(128) void k_mat(
        const float* __restrict__ rgb, const float* __restrict__ sar,
        const float* __restrict__ w_fs, const float* __restrict__ fm,
        uint2* __restrict__ xph) {
    int w = threadIdx.x;              // 0..127
    int blk = blockIdx.x;
    int b = blk / (HH / ROWS);
    int h0 = (blk % (HH / ROWS)) * ROWS;

    const float* rg0 = rgb + ((size_t)(b * 2 + 0) * HH + h0) * WW;  // uniform base
    const float* rg1 = rgb + ((size_t)(b * 2 + 1) * HH + h0) * WW;
    const float* fm0 = fm + (size_t)(b * 2 + 0) * PP * PP;
    const float* fm1 = fm + (size_t)(b * 2 + 1) * PP * PP;

    float acc0[ROWS], acc1[ROWS];
#pragma unroll
    for (int r = 0; r < ROWS; ++r) {                 // residual term
        acc0[r] = rg0[r * WW + w];
        acc1[r] = rg1[r * WW + w];
    }

#pragma unroll 4
    for (int k4 = 0; k4 < PP; k4 += 4) {
        float f0[4], f1[4];
#pragma unroll
        for (int t = 0; t < 4; ++t) {
            f0[t] = fm0[(size_t)(k4 + t) * PP + w];  // coalesced vector load
            f1[t] = fm1[(size_t)(k4 + t) * PP + w];
        }
#pragma unroll
        for (int r = 0; r < ROWS; ++r) {
            float4 a0 = *(const float4*)(rg0 + r * WW + k4);   // uniform -> s_load
            float4 a1 = *(const float4*)(rg1 + r * WW + k4);
            acc0[r] += a0.x * f0[0] + a0.y * f0[1] + a0.z * f0[2] + a0.w * f0[3];
            acc1[r] += a1.x * f1[0] + a1.y * f1[1] + a1.z * f1[2] + a1.w * f1[3];
        }
    }

    float wa = w_fs[0], wb = w_fs[1], wc = w_fs[2], wd = w_fs[3];
#pragma unroll
    for (int r = 0; r < ROWS; ++r) {
        float m0 = acc0[r], m1 = acc1[r];
        float fs0 = wa * m0 + wb * m1;
        float fs1 = wc * m0 + wd * m1;
        float s0 = sar[((size_t)(b * 2 + 0) * HH + (h0 + r)) * WW + w];
        float s1 = sar[((size_t)(b * 2 + 1) * HH + (h0 + r)) * WW + w];
        uint2 cell = make_uint2(pku(s0, s1), pku(fs0, fs1));
        xph[((size_t)b * HP + (h0 + r + 1)) * WP + (w + 1)] = cell;
    }
}

// ---------------------------------------------------------------------------
// Kernel 3: offset conv (dot2, weights packed in-register from immutable w_p)
// + deformable bilinear sampling (f16 interp, f32 accumulate) + combine.
// FOUR vertically-adjacent pixels per thread: each weight pack (s_load x2 +
// v_cvt_pkrtz) amortized over 4 dot2 uses; neighborhood rows shared (6 rows
// for 4 pixels).
// ---------------------------------------------------------------------------
__global__ __launch_bounds__(256) void k_deform(
        const float* __restrict__ w_p, const float* __restrict__ b_p,
        const float* __restrict__ w_dc, const uint2* __restrict__ xph,
        float* __restrict__ out) {
    int idx = blockIdx.x * 256 + threadIdx.x;   // 0 .. B*(H/4)*W-1
    int b = idx >> 16;                          // (H/4)*W = 65536 = 2^16
    int rem = idx & ((HH / 4) * WW - 1);
    int h4 = rem >> 7;                          // W = 128 = 2^7
    int w = rem & (WW - 1);
    int h = h4 * 4;                             // pixels h..h+3

    const uint2* xb = xph + (size_t)b * HP * WP;

    // 6 rows x 3 cols packed-f16 neighborhood (covers 4 output rows)
    uint2 nbh[6][3];
#pragma unroll
    for (int dy = 0; dy < 6; ++dy)
#pragma unroll
        for (int dx = 0; dx < 3; ++dx)
            nbh[dy][dx] = xb[(h + dy) * WP + (w + dx)];

    // ---- offset conv: off[p][r], weights packed in-register, 4x amortized --
    float off[4][18];
#pragma unroll
    for (int r = 0; r < 18; ++r) {
        float bias = b_p[r];                    // uniform -> s_load (input buf)
#pragma unroll
        for (int p = 0; p < 4; ++p) off[p][r] = bias;
    }
#pragma unroll
    for (int t = 0; t < 9; ++t) {
        int ky = t / 3, kx = t % 3;
#pragma unroll
        for (int q = 0; q < 2; ++q) {           // channel pair
#pragma unroll
            for (int r = 0; r < 18; ++r) {
                unsigned wk = pku(w_p[r * 36 + (2 * q) * 9 + t],
                                  w_p[r * 36 + (2 * q + 1) * 9 + t]);
#pragma unroll
                for (int p = 0; p < 4; ++p) {
                    uint2 c = nbh[ky + p][kx];
                    off[p][r] = dot2(q == 0 ? b2h(c.x) : b2h(c.y), wk, off[p][r]);
                }
            }
        }
    }

    // ---- bilinear sampling + deform conv combine ----
    float acc0[4] = {0.f, 0.f, 0.f, 0.f};
    float acc1[4] = {0.f, 0.f, 0.f, 0.f};
#pragma unroll
    for (int n = 0; n < 9; ++n) {
        int pny = n / 3 - 1;
        int pnx = n % 3 - 1;
        unsigned wd00 = pku(w_dc[0 * 36 + 0 * 9 + n], w_dc[0 * 36 + 1 * 9 + n]);
        unsigned wd01 = pku(w_dc[0 * 36 + 2 * 9 + n], w_dc[0 * 36 + 3 * 9 + n]);
        unsigned wd10 = pku(w_dc[1 * 36 + 0 * 9 + n], w_dc[1 * 36 + 1 * 9 + n]);
        unsigned wd11 = pku(w_dc[1 * 36 + 2 * 9 + n], w_dc[1 * 36 + 3 * 9 + n]);
#pragma unroll
        for (int p = 0; p < 4; ++p) {
            float py = (float)(h + p + 1 + pny) + off[p][n];
            float px = (float)(w + 1 + pnx) + off[p][9 + n];
            float fy = floorf(py), fx = floorf(px);
            float y0f = fminf(fmaxf(fy, 0.f), (float)(HP - 1));
            float y1f = fminf(fmaxf(fy + 1.f, 0.f), (float)(HP - 1));
            float x0f = fminf(fmaxf(fx, 0.f), (float)(WP - 1));
            float x1f = fminf(fmaxf(fx + 1.f, 0.f), (float)(WP - 1));
            int y0 = (int)y0f, y1 = (int)y1f, x0 = (int)x0f, x1 = (int)x1f;
            float pyc = fminf(fmaxf(py, 0.f), (float)(HP - 1));
            float pxc = fminf(fmaxf(px, 0.f), (float)(WP - 1));
            float ay = 1.f + y0f - pyc;
            float by = 1.f - y1f + pyc;
            float ax = 1.f + x0f - pxc;
            float bx = 1.f - x1f + pxc;
            float g_lt = ay * ax, g_rb = by * bx, g_lb = ay * bx, g_rt = by * ax;

            int r0 = y0 * WP, r1 = y1 * WP;     // int32 addressing
            uint2 clt = xb[r0 + x0];
            uint2 crb = xb[r1 + x1];
            uint2 clb = xb[r0 + x1];
            uint2 crt = xb[r1 + x0];

            half2v glt = b2h(pku(g_lt, g_lt));
            half2v grb = b2h(pku(g_rb, g_rb));
            half2v glb = b2h(pku(g_lb, g_lb));
            half2v grt = b2h(pku(g_rt, g_rt));

            half2v v01 = glt * b2h(clt.x) + grb * b2h(crb.x)
                       + glb * b2h(clb.x) + grt * b2h(crt.x);
            half2v v23 = glt * b2h(clt.y) + grb * b2h(crb.y)
                       + glb * b2h(clb.y) + grt * b2h(crt.y);

            acc0[p] = dot2(v01, wd00, acc0[p]);
            acc0[p] = dot2(v23, wd01, acc0[p]);
            acc1[p] = dot2(v01, wd10, acc1[p]);
            acc1[p] = dot2(v23, wd11, acc1[p]);
        }
    }
#pragma unroll
    for (int p = 0; p < 4; ++p) {
        out[((size_t)(b * 2 + 0) * HH + (h + p)) * WW + w] = acc0[p];
        out[((size_t)(b * 2 + 1) * HH + (h + p)) * WW + w] = acc1[p];
    }
}

// ---------------------------------------------------------------------------
extern "C" void kernel_launch(void* const* d_in, const int* in_sizes, int n_in,
                              void* d_out, int out_size, void* d_ws, size_t ws_size,
                              hipStream_t stream) {
    const float* rgb  = (const float*)d_in[0];
    const float* sar  = (const float*)d_in[1];
    const float* w_fm = (const float*)d_in[2];
    const float* w_fs = (const float*)d_in[3];
    const float* w_p  = (const float*)d_in[4];
    const float* b_p  = (const float*)d_in[5];
    const float* w_dc = (const float*)d_in[6];
    float* out = (float*)d_out;

    // ws layout: fm [131072 f32] | xph [B*HP*WP uint2]
    float* ws = (float*)d_ws;
    float* fm = ws;
    uint2* xph = (uint2*)(ws + 131072);                       // 8B aligned

    k_pad<<<(BB * BORDER_PER_B + 255) / 256, 256, 0, stream>>>(xph);
    k_fm<<<BB * 128, 128, 0, stream>>>(rgb, w_fm, fm);
    k_mat<<<BB * (HH / ROWS), 128, 0, stream>>>(rgb, sar, w_fs, fm, xph);
    k_deform<<<(BB * (HH / 4) * WW) / 256, 256, 0, stream>>>(w_p, b_p, w_dc, xph, out);
}

// Round 6
// 72.572 us; speedup vs baseline: 1.6619x; 1.6619x over previous
//
#include <hip/hip_runtime.h>
#include <math.h>

#define BB 4
#define HH 2048
#define WW 128
#define HP (HH + 2)   // 2050
#define WP (WW + 2)   // 130
#define PP 128        // pooled size
#define ROWS 4

#define BORDER_PER_B (2 * WP + 2 * (HP - 2))   // 4356

// ---------------------------------------------------------------------------
// Kernel 0: zero the pad border of xp ([B][HP][WP] float4 cells).
// Interior is fully overwritten by k_mat each call.
// ---------------------------------------------------------------------------
__global__ void k_pad(float4* __restrict__ xp) {
    int i = blockIdx.x * 256 + threadIdx.x;
    if (i >= BB * BORDER_PER_B) return;
    int b = i / BORDER_PER_B;
    int r = i - b * BORDER_PER_B;
    int row, col;
    if (r < WP)          { row = 0;      col = r; }
    else if (r < 2 * WP) { row = HP - 1; col = r - WP; }
    else {
        int j = r - 2 * WP;
        row = 1 + (j >> 1);
        col = (j & 1) ? (WP - 1) : 0;
    }
    xp[((size_t)b * HP + row) * WP + col] = make_float4(0.f, 0.f, 0.f, 0.f);
}

// ---------------------------------------------------------------------------
// Kernel 1: adaptive avg pool (exact 16x1 block mean) + 1x1 conv + sigmoid
// ---------------------------------------------------------------------------
__global__ void k_fm(const float* __restrict__ rgb, const float* __restrict__ w_fm,
                     float* __restrict__ fm) {
    int j = threadIdx.x;              // 0..127
    int bi = blockIdx.x;              // b*128 + i
    int b = bi >> 7, i = bi & 127;
    const float* r0 = rgb + ((size_t)(b * 2 + 0) * HH + (size_t)i * 16) * WW + j;
    const float* r1 = rgb + ((size_t)(b * 2 + 1) * HH + (size_t)i * 16) * WW + j;
    float s0 = 0.f, s1 = 0.f;
#pragma unroll
    for (int a = 0; a < 16; ++a) { s0 += r0[a * WW]; s1 += r1[a * WW]; }
    s0 *= (1.f / 16.f); s1 *= (1.f / 16.f);
    float f0 = w_fm[0] * s0 + w_fm[1] * s1;
    float f1 = w_fm[2] * s0 + w_fm[3] * s1;
    fm[((size_t)(b * 2 + 0) * PP + i) * PP + j] = 1.f / (1.f + expf(-f0));
    fm[((size_t)(b * 2 + 1) * PP + i) * PP + j] = 1.f / (1.f + expf(-f1));
}

// ---------------------------------------------------------------------------
// Kernel 2: mat = rgb @ fm + rgb (per b,c), fs = w_fs @ mat,
//           pack xp cell = float4 (sar0,sar1,fs0,fs1).
// ---------------------------------------------------------------------------
__global__ __launch_bounds__(128) void k_mat(
        const float* __restrict__ rgb, const float* __restrict__ sar,
        const float* __restrict__ w_fs, const float* __restrict__ fm,
        float* __restrict__ xp) {
    int w = threadIdx.x;              // 0..127
    int blk = blockIdx.x;
    int b = blk / (HH / ROWS);
    int h0 = (blk % (HH / ROWS)) * ROWS;

    const float* rg0 = rgb + ((size_t)(b * 2 + 0) * HH + h0) * WW;  // uniform base
    const float* rg1 = rgb + ((size_t)(b * 2 + 1) * HH + h0) * WW;
    const float* fm0 = fm + (size_t)(b * 2 + 0) * PP * PP;
    const float* fm1 = fm + (size_t)(b * 2 + 1) * PP * PP;

    float acc0[ROWS], acc1[ROWS];
#pragma unroll
    for (int r = 0; r < ROWS; ++r) {                 // residual term
        acc0[r] = rg0[r * WW + w];
        acc1[r] = rg1[r * WW + w];
    }

#pragma unroll 4
    for (int k4 = 0; k4 < PP; k4 += 4) {
        float f0[4], f1[4];
#pragma unroll
        for (int t = 0; t < 4; ++t) {
            f0[t] = fm0[(size_t)(k4 + t) * PP + w];  // coalesced vector load
            f1[t] = fm1[(size_t)(k4 + t) * PP + w];
        }
#pragma unroll
        for (int r = 0; r < ROWS; ++r) {
            float4 a0 = *(const float4*)(rg0 + r * WW + k4);   // uniform -> s_load
            float4 a1 = *(const float4*)(rg1 + r * WW + k4);
            acc0[r] += a0.x * f0[0] + a0.y * f0[1] + a0.z * f0[2] + a0.w * f0[3];
            acc1[r] += a1.x * f1[0] + a1.y * f1[1] + a1.z * f1[2] + a1.w * f1[3];
        }
    }

    float wa = w_fs[0], wb = w_fs[1], wc = w_fs[2], wd = w_fs[3];
#pragma unroll
    for (int r = 0; r < ROWS; ++r) {
        float m0 = acc0[r], m1 = acc1[r];
        float fs0 = wa * m0 + wb * m1;
        float fs1 = wc * m0 + wd * m1;
        float s0 = sar[((size_t)(b * 2 + 0) * HH + (h0 + r)) * WW + w];
        float s1 = sar[((size_t)(b * 2 + 1) * HH + (h0 + r)) * WW + w];
        float4 v = make_float4(s0, s1, fs0, fs1);
        *(float4*)(xp + (((size_t)b * HP + (h0 + r + 1)) * WP + (w + 1)) * 4) = v;
    }
}

// ---------------------------------------------------------------------------
// Kernel 3: offset conv (3x3, 18 ch, s_load f32 weights + v_fmac) + deformable
// bilinear sampling + 3x3 deform conv (O=2). 2 vertically-adjacent px/thread.
// __launch_bounds__(256, 2): <=256 VGPR budget -> NO scratch spills (R1-R5
// ran at VGPR 48-68 with ~110+ live values => spill-bound).
// ---------------------------------------------------------------------------
__global__ __launch_bounds__(256, 2) void k_deform(
        const float* __restrict__ w_p, const float* __restrict__ b_p,
        const float* __restrict__ w_dc, const float* __restrict__ xp,
        float* __restrict__ out) {
    int idx = blockIdx.x * 256 + threadIdx.x;   // 0 .. B*(H/2)*W-1
    int b = idx >> 17;                          // (H/2)*W = 131072 = 2^17
    int rem = idx & ((HH / 2) * WW - 1);
    int h2 = rem >> 7;                          // W = 128 = 2^7
    int w = rem & (WW - 1);
    int h = h2 * 2;                             // pixels (h,w) and (h+1,w)

    const float4* xpb = (const float4*)xp + (size_t)b * HP * WP;

    // 4 rows x 3 cols neighborhood (float4 = 4 channels per point)
    float4 nb4[4][3];
#pragma unroll
    for (int dy = 0; dy < 4; ++dy)
#pragma unroll
        for (int dx = 0; dx < 3; ++dx)
            nb4[dy][dx] = xpb[(h + dy) * WP + (w + dx)];

    // offsets for both pixels: off[p][r]
    float off[2][18];
#pragma unroll
    for (int r = 0; r < 18; ++r) {
        float bias = b_p[r];                    // uniform -> s_load
        float s0 = bias, s1 = bias;
        const float* wr = w_p + r * 36;         // [ci][ky][kx]
#pragma unroll
        for (int ky = 0; ky < 3; ++ky)
#pragma unroll
            for (int kx = 0; kx < 3; ++kx) {
                float w0 = wr[0 * 9 + ky * 3 + kx];   // uniform -> s_load
                float w1 = wr[1 * 9 + ky * 3 + kx];
                float w2 = wr[2 * 9 + ky * 3 + kx];
                float w3 = wr[3 * 9 + ky * 3 + kx];
                float4 va = nb4[ky][kx];        // pixel 0
                float4 vb = nb4[ky + 1][kx];    // pixel 1
                s0 += w0 * va.x + w1 * va.y + w2 * va.z + w3 * va.w;
                s1 += w0 * vb.x + w1 * vb.y + w2 * vb.z + w3 * vb.w;
            }
        off[0][r] = s0;
        off[1][r] = s1;
    }

#pragma unroll
    for (int p = 0; p < 2; ++p) {
        int hp_ = h + p;
        float acc0 = 0.f, acc1 = 0.f;
#pragma unroll
        for (int n = 0; n < 9; ++n) {
            int pny = n / 3 - 1;
            int pnx = n % 3 - 1;
            float py = (float)(hp_ + 1 + pny) + off[p][n];
            float px = (float)(w + 1 + pnx) + off[p][9 + n];
            float fy = floorf(py), fx = floorf(px);
            float y0f = fminf(fmaxf(fy, 0.f), (float)(HP - 1));
            float y1f = fminf(fmaxf(fy + 1.f, 0.f), (float)(HP - 1));
            float x0f = fminf(fmaxf(fx, 0.f), (float)(WP - 1));
            float x1f = fminf(fmaxf(fx + 1.f, 0.f), (float)(WP - 1));
            int y0 = (int)y0f, y1 = (int)y1f, x0 = (int)x0f, x1 = (int)x1f;
            float pyc = fminf(fmaxf(py, 0.f), (float)(HP - 1));
            float pxc = fminf(fmaxf(px, 0.f), (float)(WP - 1));
            float ay = 1.f + y0f - pyc;
            float by = 1.f - y1f + pyc;
            float ax = 1.f + x0f - pxc;
            float bx = 1.f - x1f + pxc;
            float g_lt = ay * ax, g_rb = by * bx, g_lb = ay * bx, g_rt = by * ax;

            int r0 = y0 * WP, r1 = y1 * WP;     // int32 addressing
            float4 v_lt = xpb[r0 + x0];
            float4 v_rb = xpb[r1 + x1];
            float4 v_lb = xpb[r0 + x1];
            float4 v_rt = xpb[r1 + x0];

            float vx = g_lt * v_lt.x + g_rb * v_rb.x + g_lb * v_lb.x + g_rt * v_rt.x;
            float vy = g_lt * v_lt.y + g_rb * v_rb.y + g_lb * v_lb.y + g_rt * v_rt.y;
            float vz = g_lt * v_lt.z + g_rb * v_rb.z + g_lb * v_lb.z + g_rt * v_rt.z;
            float vw = g_lt * v_lt.w + g_rb * v_rb.w + g_lb * v_lb.w + g_rt * v_rt.w;

            acc0 += vx * w_dc[0 * 36 + 0 * 9 + n] + vy * w_dc[0 * 36 + 1 * 9 + n]
                  + vz * w_dc[0 * 36 + 2 * 9 + n] + vw * w_dc[0 * 36 + 3 * 9 + n];
            acc1 += vx * w_dc[1 * 36 + 0 * 9 + n] + vy * w_dc[1 * 36 + 1 * 9 + n]
                  + vz * w_dc[1 * 36 + 2 * 9 + n] + vw * w_dc[1 * 36 + 3 * 9 + n];
        }
        out[((size_t)(b * 2 + 0) * HH + hp_) * WW + w] = acc0;
        out[((size_t)(b * 2 + 1) * HH + hp_) * WW + w] = acc1;
    }
}

// ---------------------------------------------------------------------------
extern "C" void kernel_launch(void* const* d_in, const int* in_sizes, int n_in,
                              void* d_out, int out_size, void* d_ws, size_t ws_size,
                              hipStream_t stream) {
    const float* rgb  = (const float*)d_in[0];
    const float* sar  = (const float*)d_in[1];
    const float* w_fm = (const float*)d_in[2];
    const float* w_fs = (const float*)d_in[3];
    const float* w_p  = (const float*)d_in[4];
    const float* b_p  = (const float*)d_in[5];
    const float* w_dc = (const float*)d_in[6];
    float* out = (float*)d_out;

    // ws layout: fm [131072 f32] | xp [B*HP*WP float4]
    float* ws = (float*)d_ws;
    float* fm = ws;
    float* xp = ws + 131072;                           // 16B aligned

    k_pad<<<(BB * BORDER_PER_B + 255) / 256, 256, 0, stream>>>((float4*)xp);
    k_fm<<<BB * 128, 128, 0, stream>>>(rgb, w_fm, fm);
    k_mat<<<BB * (HH / ROWS), 128, 0, stream>>>(rgb, sar, w_fs, fm, xp);
    k_deform<<<(BB * (HH / 2) * WW) / 256, 256, 0, stream>>>(w_p, b_p, w_dc, xp, out);
}